// Round 9
// baseline (2359.494 us; speedup 1.0000x reference)
//
#include <hip/hip_runtime.h>

#define T 3
#define E 500000
#define F 128
#define H 64
#define B 1024

#define BLK_E 64
#define LE 65   // xs row stride (odd -> 2-way-free lane-indexed reads)

#define EMASK 0x7FFFF  // e < 2^19; graph packed in bits 19..28

// ---- helpers ----------------------------------------------------------

__device__ __forceinline__ float tanh_fast(float x) {
  // tanh(x) = 1 - 2/(exp(2x)+1); robust at +-inf
  float e = __expf(2.0f * x);
  return 1.0f - 2.0f / (e + 1.0f);
}

// ---- kernel 0: zero accumulators + counters ---------------------------

__global__ void k_init(float* __restrict__ acc, float* __restrict__ ssum,
                       unsigned* __restrict__ cnt) {
  int idx = blockIdx.x * blockDim.x + threadIdx.x;
  if (idx < T * B * F) acc[idx] = 0.0f;
  if (idx < T * B) {
    ssum[idx] = 0.0f;
    cnt[idx] = 0u;
  }
}

// ---- kernel 1: histogram of edges per (t, graph) ----------------------

__global__ __launch_bounds__(256) void k_hist(
    const int* __restrict__ batch, unsigned* __restrict__ cnt) {
  int t = blockIdx.y;
  int e = blockIdx.x * 256 + threadIdx.x;
  if (e >= E) return;
  atomicAdd(&cnt[t * B + batch[(size_t)t * E + e]], 1u);
}

// ---- kernel 2: prefix sums --------------------------------------------

__global__ void k_scan(const unsigned* __restrict__ cnt,
                       unsigned* __restrict__ cursor) {
  __shared__ unsigned s[B];
  int tid = threadIdx.x;
  for (int t = 0; t < T; ++t) {
    unsigned v = cnt[t * B + tid];
    s[tid] = v;
    __syncthreads();
    for (int d = 1; d < B; d <<= 1) {
      unsigned x = (tid >= d) ? s[tid - d] : 0u;
      __syncthreads();
      s[tid] += x;
      __syncthreads();
    }
    cursor[t * B + tid] = s[tid] - v;  // exclusive scan
    __syncthreads();
  }
}

// ---- kernel 3: counting-sort scatter; pack (graph<<19)|edge -----------

__global__ __launch_bounds__(256) void k_scatter(
    const int* __restrict__ batch, unsigned* __restrict__ cursor,
    unsigned* __restrict__ eid) {
  int t = blockIdx.y;
  int e = blockIdx.x * 256 + threadIdx.x;
  if (e >= E) return;
  int b = batch[(size_t)t * E + e];
  unsigned pos = atomicAdd(&cursor[t * B + b], 1u);
  eid[(size_t)t * E + pos] = (unsigned)e | ((unsigned)b << 19);
}

// ---- kernel 4: fused score + exp + segment-aggregated scatter ---------
// GEMM shape: wave = 16-j slab (wave-uniform -> weights on the SCALAR pipe
// via s_load + v_fmac(v,s,v)), lane = edge (x = ONE ds_read_b32 per f per
// wave, banks (f+lane)%32 2-way free). LDS-pipe instrs cut 4x vs r5-r8.
// Edges sorted by graph -> one atomic per (segment,f). No max-subtraction:
// |score| <= ||W2||_1 ~ 6, exp() cannot overflow.

__global__ __launch_bounds__(256, 4) void k_fused(
    const float* __restrict__ ea, const unsigned* __restrict__ eid,
    const float* __restrict__ W1, const float* __restrict__ b1,
    const float* __restrict__ W2, const float* __restrict__ b2,
    float* __restrict__ acc, float* __restrict__ ssum) {
  __shared__ float xs[F * LE];   // 33.3 KB  [f][e] pad-65
  __shared__ float red[4 * 64];
  __shared__ float exl[BLK_E];
  __shared__ int bbl[BLK_E];
  __shared__ int eidl[BLK_E];

  int t = blockIdx.y;
  int tid = threadIdx.x;
  int e0 = blockIdx.x * BLK_E;

  if (tid < BLK_E) {
    int p = e0 + tid;
    int pc = p < E ? p : E - 1;  // clamp tail; predicated out later
    unsigned pk = eid[(size_t)t * E + pc];
    eidl[tid] = (int)(pk & EMASK);
    bbl[tid] = (int)(pk >> 19);
  }
  __syncthreads();

  // register-staged gather: 8 independent dwordx4 in flight, transpose to xs
  const float* eag = ea + (size_t)t * E * (size_t)F;
  int c = tid & 31;   // float4 column
  int r0 = tid >> 5;  // base row
  float4 v[8];
#pragma unroll
  for (int k = 0; k < 8; ++k) {
    int id = eidl[r0 + 8 * k];
    v[k] = *(const float4*)(eag + (size_t)id * F + 4 * c);
  }
#pragma unroll
  for (int k = 0; k < 8; ++k) {
    int r = r0 + 8 * k;
    xs[(4 * c + 0) * LE + r] = v[k].x;
    xs[(4 * c + 1) * LE + r] = v[k].y;
    xs[(4 * c + 2) * LE + r] = v[k].z;
    xs[(4 * c + 3) * LE + r] = v[k].w;
  }
  __syncthreads();

  // ---- GEMM: wave-uniform weight slab (scalar pipe), lane = edge ----
  int lane = tid & 63;
  int wslab = __builtin_amdgcn_readfirstlane(tid >> 6);  // 0..3
  const float* wt = W1 + (size_t)t * F * H + 16 * wslab; // wt[f*H + j]

  float a[16];
#pragma unroll
  for (int j = 0; j < 16; ++j) a[j] = 0.0f;

#pragma unroll 4
  for (int f = 0; f < F; ++f) {
    float x = xs[f * LE + lane];       // one b32 per wave per f
#pragma unroll
    for (int j = 0; j < 16; ++j)
      a[j] = fmaf(x, wt[f * H + j], a[j]);  // v_fmac(v, s, v)
  }

  // epilogue: tanh + W2 slab dot -> per-edge partial for this j-slab
  float ps = 0.0f;
#pragma unroll
  for (int j = 0; j < 16; ++j) {
    float h = tanh_fast(a[j] + b1[t * H + 16 * wslab + j]);
    ps = fmaf(h, W2[t * H + 16 * wslab + j], ps);
  }
  red[wslab * 64 + lane] = ps;   // banks lane%32: 2-way free
  __syncthreads();

  if (tid < BLK_E) {
    float sc = ((red[tid] + red[64 + tid]) + (red[128 + tid] + red[192 + tid]))
               + b2[t];
    exl[tid] = __expf(sc);
  }
  __syncthreads();

  // ssum atomic AFTER the barrier: fire-and-forget, overlaps scatter
  if (tid < BLK_E && e0 + tid < E)
    atomicAdd(&ssum[t * B + bbl[tid]], exl[tid]);

  // segment-aggregated scatter: wave wv owns 16 sorted edges; lane l owns
  // f=l and f=l+64; flush one atomic pair per segment.
  int wv = tid >> 6;
  int l = tid & 63;
  float* acct = acc + (size_t)t * B * F;
  float a0 = 0.0f, a1 = 0.0f;
  int prev = -1;
  for (int i = 0; i < 16; ++i) {
    int eloc = wv * 16 + i;
    if (e0 + eloc >= E) break;        // uniform (tail block only)
    int b = bbl[eloc];                // wave-uniform
    if (b != prev) {
      if (prev >= 0) {
        atomicAdd(acct + (size_t)prev * F + l, a0);
        atomicAdd(acct + (size_t)prev * F + l + 64, a1);
      }
      prev = b;
      a0 = 0.0f;
      a1 = 0.0f;
    }
    float exv = exl[eloc];
    a0 = fmaf(xs[l * LE + eloc], exv, a0);
    a1 = fmaf(xs[(l + 64) * LE + eloc], exv, a1);
  }
  if (prev >= 0) {
    atomicAdd(acct + (size_t)prev * F + l, a0);
    atomicAdd(acct + (size_t)prev * F + l + 64, a1);
  }
}

// ---- kernel 5: normalize + mean over types ----------------------------

__global__ __launch_bounds__(256) void k_final(
    const float* __restrict__ acc, const float* __restrict__ ssum,
    float* __restrict__ out) {
  int idx = blockIdx.x * 256 + threadIdx.x;  // b*F + f
  if (idx >= B * F) return;
  int b = idx >> 7;
  float s = 0.0f;
#pragma unroll
  for (int t = 0; t < T; ++t)
    s += acc[(size_t)t * B * F + idx] / ssum[t * B + b];
  out[idx] = s * (1.0f / 3.0f);
}

// ---- launch ------------------------------------------------------------

extern "C" void kernel_launch(void* const* d_in, const int* in_sizes, int n_in,
                              void* d_out, int out_size, void* d_ws, size_t ws_size,
                              hipStream_t stream) {
  const float* ea    = (const float*)d_in[0];
  const int*   batch = (const int*)d_in[1];
  const float* W1    = (const float*)d_in[2];
  const float* b1    = (const float*)d_in[3];
  const float* W2    = (const float*)d_in[4];
  const float* b2    = (const float*)d_in[5];
  float* out = (float*)d_out;

  // workspace: acc 1.5MB + ssum/cnt/cursor 36KB + eid 6MB  (~7.6 MB)
  float*    acc    = (float*)d_ws;                     // T*B*F f32
  float*    ssum   = acc + (size_t)T * B * F;          // T*B f32
  unsigned* cnt    = (unsigned*)(ssum + T * B);        // T*B u32
  unsigned* cursor = cnt + T * B;                      // T*B u32
  unsigned* eid    = cursor + T * B;                   // T*E u32

  k_init<<<(T * B * F + 255) / 256, 256, 0, stream>>>(acc, ssum, cnt);

  dim3 ge((E + 255) / 256, T);
  k_hist<<<ge, 256, 0, stream>>>(batch, cnt);
  k_scan<<<1, B, 0, stream>>>(cnt, cursor);
  k_scatter<<<ge, 256, 0, stream>>>(batch, cursor, eid);

  dim3 gs((E + BLK_E - 1) / BLK_E, T);
  k_fused<<<gs, 256, 0, stream>>>(ea, eid, W1, b1, W2, b2, acc, ssum);

  k_final<<<(B * F + 255) / 256, 256, 0, stream>>>(acc, ssum, out);
}

// Round 10
// 648.775 us; speedup vs baseline: 3.6368x; 3.6368x over previous
//
#include <hip/hip_runtime.h>

#define T 3
#define E 500000
#define F 128
#define H 64
#define B 1024

#define BLK_E 64
#define EMASK 0x7FFFF  // e < 2^19; graph packed in bits 19..28

typedef __attribute__((ext_vector_type(8))) short short8;
typedef __attribute__((ext_vector_type(4))) float f32x4;

// ---- helpers ----------------------------------------------------------

__device__ __forceinline__ float tanh_fast(float x) {
  float e = __expf(2.0f * x);
  return 1.0f - 2.0f / (e + 1.0f);
}
__device__ __forceinline__ unsigned short bfr(float x) {  // f32->bf16 RNE
  unsigned u = __float_as_uint(x);
  return (unsigned short)((u + 0x7FFFu + ((u >> 16) & 1u)) >> 16);
}
__device__ __forceinline__ float bft(unsigned short h) {
  return __uint_as_float(((unsigned)h) << 16);
}

// ---- kernel 0: zero accumulators + pack W1 into MFMA B-fragments ------
// Wpack[t][p(hi/lo)][nt(4)][ks(4)][lane(64)][8]: lane l holds B-frag
// col j = nt*16+(l&15), k = ks*32+(l>>4)*8 + 0..7  (B^T row-major conv.)

__global__ void k_init(const float* __restrict__ W1, float* __restrict__ acc,
                       float* __restrict__ ssum, unsigned* __restrict__ cnt,
                       unsigned short* __restrict__ Wpack) {
  int idx = blockIdx.x * blockDim.x + threadIdx.x;
  if (idx < T * B * F) acc[idx] = 0.0f;
  if (idx < T * B) {
    ssum[idx] = 0.0f;
    cnt[idx] = 0u;
  }
  if (idx < T * 2 * 4 * 4 * 64) {
    int lane = idx & 63;
    int r2 = idx >> 6;
    int ks = r2 & 3;
    int nt = (r2 >> 2) & 3;
    int p = (r2 >> 4) & 1;
    int t = r2 >> 5;
    int j = nt * 16 + (lane & 15);
#pragma unroll
    for (int e = 0; e < 8; ++e) {
      int f = ks * 32 + (lane >> 4) * 8 + e;
      float w = W1[((size_t)t * F + f) * H + j];
      unsigned short hi = bfr(w);
      unsigned short v = p ? bfr(w - bft(hi)) : hi;
      Wpack[(size_t)idx * 8 + e] = v;
    }
  }
}

// ---- kernel 1: LDS-local histogram ------------------------------------

__global__ __launch_bounds__(256) void k_hist(
    const int* __restrict__ batch, unsigned* __restrict__ cnt) {
  __shared__ unsigned h[B];
  int t = blockIdx.y;
  for (int i = threadIdx.x; i < B; i += 256) h[i] = 0u;
  __syncthreads();
  int base = blockIdx.x * 4096;
  int end = base + 4096 < E ? base + 4096 : E;
  for (int i = base + threadIdx.x; i < end; i += 256)
    atomicAdd(&h[batch[(size_t)t * E + i]], 1u);
  __syncthreads();
  for (int i = threadIdx.x; i < B; i += 256) {
    unsigned v = h[i];
    if (v) atomicAdd(&cnt[t * B + i], v);
  }
}

// ---- kernel 2: prefix sums --------------------------------------------

__global__ void k_scan(const unsigned* __restrict__ cnt,
                       unsigned* __restrict__ cursor) {
  __shared__ unsigned s[B];
  int tid = threadIdx.x;
  for (int t = 0; t < T; ++t) {
    unsigned v = cnt[t * B + tid];
    s[tid] = v;
    __syncthreads();
    for (int d = 1; d < B; d <<= 1) {
      unsigned x = (tid >= d) ? s[tid - d] : 0u;
      __syncthreads();
      s[tid] += x;
      __syncthreads();
    }
    cursor[t * B + tid] = s[tid] - v;  // exclusive
    __syncthreads();
  }
}

// ---- kernel 3: counting-sort scatter; pack (graph<<19)|edge -----------

__global__ __launch_bounds__(256) void k_scatter(
    const int* __restrict__ batch, unsigned* __restrict__ cursor,
    unsigned* __restrict__ eid) {
  int t = blockIdx.y;
  int e = blockIdx.x * 256 + threadIdx.x;
  if (e >= E) return;
  int b = batch[(size_t)t * E + e];
  unsigned pos = atomicAdd(&cursor[t * B + b], 1u);
  eid[(size_t)t * E + pos] = (unsigned)e | ((unsigned)b << 19);
}

// ---- kernel 4: MFMA fused score + exp + segment-aggregated scatter ----
// ea tile -> bf16 hi/lo in LDS (XOR-swizzled rows, m214 pattern). GEMM via
// mfma_f32_16x16x32_bf16, 3 passes (AhiWhi + AhiWlo + AloWhi) -> rel err
// ~1.5e-5. C/D layout (verified m89): col=lane&15, row=(lane>>4)*4+reg.
// Scatter numerator uses hi+lo (=ea to ~4e-6). One atomic per (segment,f).

__global__ __launch_bounds__(256, 4) void k_fused(
    const float* __restrict__ ea, const unsigned* __restrict__ eid,
    const unsigned short* __restrict__ Wpack, const float* __restrict__ b1,
    const float* __restrict__ W2, const float* __restrict__ b2,
    float* __restrict__ accg, float* __restrict__ ssum) {
  __shared__ unsigned short hi_t[BLK_E * F];  // 16 KB, row-swizzled
  __shared__ unsigned short lo_t[BLK_E * F];  // 16 KB
  __shared__ float scl[BLK_E];
  __shared__ float exl[BLK_E];
  __shared__ int bbl[BLK_E];
  __shared__ int eidl[BLK_E];

  int t = blockIdx.y;
  int tid = threadIdx.x;
  int e0 = blockIdx.x * BLK_E;

  if (tid < BLK_E) {
    int p = e0 + tid;
    int pc = p < E ? p : E - 1;  // clamp tail; excluded later
    unsigned pk = eid[(size_t)t * E + pc];
    eidl[tid] = (int)(pk & EMASK);
    bbl[tid] = (int)(pk >> 19);
  }
  __syncthreads();

  // ---- stage: gather rows, convert to bf16 hi/lo, swizzled LDS write ----
  // thread covers 8 rows x 4 f: load k -> row k*8+(tid>>5), f0=(tid&31)*4.
  const float* eag = ea + (size_t)t * E * (size_t)F;
  int f0 = (tid & 31) * 4;
  float4 v[8];
#pragma unroll
  for (int k = 0; k < 8; ++k) {
    int r = k * 8 + (tid >> 5);
    v[k] = *(const float4*)(eag + (size_t)eidl[r] * F + f0);
  }
#pragma unroll
  for (int k = 0; k < 8; ++k) {
    int r = k * 8 + (tid >> 5);
    unsigned short h0 = bfr(v[k].x), h1 = bfr(v[k].y);
    unsigned short h2 = bfr(v[k].z), h3 = bfr(v[k].w);
    ushort4 hv = {h0, h1, h2, h3};
    ushort4 lv = {bfr(v[k].x - bft(h0)), bfr(v[k].y - bft(h1)),
                  bfr(v[k].z - bft(h2)), bfr(v[k].w - bft(h3))};
    int off = (r * 256 + f0 * 2) ^ ((r & 7) << 4);  // 8B-aligned
    *(ushort4*)((char*)hi_t + off) = hv;
    *(ushort4*)((char*)lo_t + off) = lv;
  }
  __syncthreads();

  // ---- MFMA GEMM: wave w -> rows w*16..w*16+15; N=64 as 4 subtiles ----
  int l = tid & 63;
  int w = tid >> 6;
  f32x4 acc[4];
#pragma unroll
  for (int nt = 0; nt < 4; ++nt) acc[nt] = (f32x4){0.f, 0.f, 0.f, 0.f};

  const unsigned short* wpt = Wpack + (size_t)t * 16384;
  int arow = w * 16 + (l & 15);
  int abase = arow * 256;
  int aswz = (arow & 7) << 4;
#pragma unroll
  for (int ks = 0; ks < 4; ++ks) {
    int abyte = (abase + (ks * 32 + (l >> 4) * 8) * 2) ^ aswz;  // 16B-align
    short8 ahi = *(const short8*)((const char*)hi_t + abyte);
    short8 alo = *(const short8*)((const char*)lo_t + abyte);
#pragma unroll
    for (int nt = 0; nt < 4; ++nt) {
      short8 bhi = *(const short8*)(wpt + ((nt * 4 + ks) * 64 + l) * 8);
      short8 blo = *(const short8*)(wpt + 8192 + ((nt * 4 + ks) * 64 + l) * 8);
      acc[nt] = __builtin_amdgcn_mfma_f32_16x16x32_bf16(ahi, bhi, acc[nt], 0, 0, 0);
      acc[nt] = __builtin_amdgcn_mfma_f32_16x16x32_bf16(ahi, blo, acc[nt], 0, 0, 0);
      acc[nt] = __builtin_amdgcn_mfma_f32_16x16x32_bf16(alo, bhi, acc[nt], 0, 0, 0);
    }
  }

  // ---- epilogue: tanh + W2 dot; reduce over j (16-lane groups) ----
  int jb = l & 15;
  float p0 = 0.f, p1 = 0.f, p2 = 0.f, p3 = 0.f;
#pragma unroll
  for (int nt = 0; nt < 4; ++nt) {
    float b1v = b1[t * H + nt * 16 + jb];
    float w2v = W2[t * H + nt * 16 + jb];
    p0 = fmaf(tanh_fast(acc[nt][0] + b1v), w2v, p0);
    p1 = fmaf(tanh_fast(acc[nt][1] + b1v), w2v, p1);
    p2 = fmaf(tanh_fast(acc[nt][2] + b1v), w2v, p2);
    p3 = fmaf(tanh_fast(acc[nt][3] + b1v), w2v, p3);
  }
#pragma unroll
  for (int m = 1; m < 16; m <<= 1) {
    p0 += __shfl_xor(p0, m);
    p1 += __shfl_xor(p1, m);
    p2 += __shfl_xor(p2, m);
    p3 += __shfl_xor(p3, m);
  }
  if (jb == 0) {
    int rb = w * 16 + (l >> 4) * 4;  // row = (lane>>4)*4 + reg (m89)
    scl[rb + 0] = p0;
    scl[rb + 1] = p1;
    scl[rb + 2] = p2;
    scl[rb + 3] = p3;
  }
  __syncthreads();
  if (tid < BLK_E) exl[tid] = __expf(scl[tid] + b2[t]);
  __syncthreads();

  // ---- segment-aggregated scatter + ssum (sorted edges) ----
  // wave wv owns 16 edges; lane ll owns f=2ll, 2ll+1 (one b32 covers both).
  int wv = tid >> 6;
  int ll = tid & 63;
  float* acct = accg + (size_t)t * B * F;
  float a0 = 0.f, a1 = 0.f, asum = 0.f;
  int prev = -1;
  for (int i = 0; i < 16; ++i) {
    int eloc = wv * 16 + i;
    if (e0 + eloc >= E) break;  // wave-uniform (tail block only)
    int b = bbl[eloc];          // wave-uniform
    if (b != prev) {
      if (prev >= 0) {
        atomicAdd(acct + (size_t)prev * F + 2 * ll, a0);
        atomicAdd(acct + (size_t)prev * F + 2 * ll + 1, a1);
        if (ll == 0) atomicAdd(&ssum[t * B + prev], asum);
      }
      prev = b;
      a0 = 0.f;
      a1 = 0.f;
      asum = 0.f;
    }
    int off = (eloc * 256 + ll * 4) ^ ((eloc & 7) << 4);
    unsigned hv = *(const unsigned*)((const char*)hi_t + off);
    unsigned lv = *(const unsigned*)((const char*)lo_t + off);
    float x0 = bft((unsigned short)(hv & 0xFFFFu)) + bft((unsigned short)(lv & 0xFFFFu));
    float x1 = bft((unsigned short)(hv >> 16)) + bft((unsigned short)(lv >> 16));
    float exv = exl[eloc];
    a0 = fmaf(x0, exv, a0);
    a1 = fmaf(x1, exv, a1);
    asum += exv;
  }
  if (prev >= 0) {
    atomicAdd(acct + (size_t)prev * F + 2 * ll, a0);
    atomicAdd(acct + (size_t)prev * F + 2 * ll + 1, a1);
    if (ll == 0) atomicAdd(&ssum[t * B + prev], asum);
  }
}

// ---- kernel 5: normalize + mean over types ----------------------------

__global__ __launch_bounds__(256) void k_final(
    const float* __restrict__ acc, const float* __restrict__ ssum,
    float* __restrict__ out) {
  int idx = blockIdx.x * 256 + threadIdx.x;  // b*F + f
  if (idx >= B * F) return;
  int b = idx >> 7;
  float s = 0.0f;
#pragma unroll
  for (int t = 0; t < T; ++t)
    s += acc[(size_t)t * B * F + idx] / ssum[t * B + b];
  out[idx] = s * (1.0f / 3.0f);
}

// ---- launch ------------------------------------------------------------

extern "C" void kernel_launch(void* const* d_in, const int* in_sizes, int n_in,
                              void* d_out, int out_size, void* d_ws, size_t ws_size,
                              hipStream_t stream) {
  const float* ea    = (const float*)d_in[0];
  const int*   batch = (const int*)d_in[1];
  const float* W1    = (const float*)d_in[2];
  const float* b1    = (const float*)d_in[3];
  const float* W2    = (const float*)d_in[4];
  const float* b2    = (const float*)d_in[5];
  float* out = (float*)d_out;

  // workspace: acc 1.5MB + ssum/cnt/cursor 36KB + eid 6MB + Wpack 96KB
  float*          acc    = (float*)d_ws;                  // T*B*F f32
  float*          ssum   = acc + (size_t)T * B * F;       // T*B f32
  unsigned*       cnt    = (unsigned*)(ssum + T * B);     // T*B u32
  unsigned*       cursor = cnt + T * B;                   // T*B u32
  unsigned*       eid    = cursor + T * B;                // T*E u32
  unsigned short* Wpack  = (unsigned short*)(eid + (size_t)T * E);  // 49152 u16

  k_init<<<(T * B * F + 255) / 256, 256, 0, stream>>>(W1, acc, ssum, cnt, Wpack);

  dim3 gh((E + 4095) / 4096, T);
  k_hist<<<gh, 256, 0, stream>>>(batch, cnt);
  k_scan<<<1, B, 0, stream>>>(cnt, cursor);
  dim3 ge((E + 255) / 256, T);
  k_scatter<<<ge, 256, 0, stream>>>(batch, cursor, eid);

  dim3 gs((E + BLK_E - 1) / BLK_E, T);
  k_fused<<<gs, 256, 0, stream>>>(ea, eid, Wpack, b1, W2, b2, acc, ssum);

  k_final<<<(B * F + 255) / 256, 256, 0, stream>>>(acc, ssum, out);
}

// Round 11
// 430.282 us; speedup vs baseline: 5.4836x; 1.5078x over previous
//
#include <hip/hip_runtime.h>

#define T 3
#define E 500000
#define F 128
#define H 64
#define B 1024

#define BLK_E 64
#define EMASK 0x7FFFF  // e < 2^19; graph packed in bits 19..28
#define PB 1024        // blocks per type in k_fused

typedef __attribute__((ext_vector_type(8))) short short8;
typedef __attribute__((ext_vector_type(4))) float f32x4;

// ---- helpers ----------------------------------------------------------

__device__ __forceinline__ float tanh_fast(float x) {
  float e = __expf(2.0f * x);
  return 1.0f - 2.0f / (e + 1.0f);
}
__device__ __forceinline__ unsigned short bfr(float x) {  // f32->bf16 RNE
  unsigned u = __float_as_uint(x);
  return (unsigned short)((u + 0x7FFFu + ((u >> 16) & 1u)) >> 16);
}
__device__ __forceinline__ float bft(unsigned short h) {
  return __uint_as_float(((unsigned)h) << 16);
}

// ---- kernel 0: zero accumulators + pack W1 into MFMA B-fragments ------
// Wpack[t][p(hi/lo)][nt(4)][ks(4)][lane(64)][8]: lane l holds B-frag
// col j = nt*16+(l&15), k = ks*32+(l>>4)*8 + 0..7

__global__ void k_init(const float* __restrict__ W1, float* __restrict__ acc,
                       float* __restrict__ ssum, unsigned* __restrict__ cnt,
                       unsigned short* __restrict__ Wpack) {
  int idx = blockIdx.x * blockDim.x + threadIdx.x;
  if (idx < T * B * F) acc[idx] = 0.0f;
  if (idx < T * B) {
    ssum[idx] = 0.0f;
    cnt[idx] = 0u;
  }
  if (idx < T * 2 * 4 * 4 * 64) {
    int lane = idx & 63;
    int r2 = idx >> 6;
    int ks = r2 & 3;
    int nt = (r2 >> 2) & 3;
    int p = (r2 >> 4) & 1;
    int t = r2 >> 5;
    int j = nt * 16 + (lane & 15);
#pragma unroll
    for (int e = 0; e < 8; ++e) {
      int f = ks * 32 + (lane >> 4) * 8 + e;
      float w = W1[((size_t)t * F + f) * H + j];
      unsigned short hi = bfr(w);
      unsigned short v = p ? bfr(w - bft(hi)) : hi;
      Wpack[(size_t)idx * 8 + e] = v;
    }
  }
}

// ---- kernel 1: LDS-local histogram ------------------------------------

__global__ __launch_bounds__(256) void k_hist(
    const int* __restrict__ batch, unsigned* __restrict__ cnt) {
  __shared__ unsigned h[B];
  int t = blockIdx.y;
  for (int i = threadIdx.x; i < B; i += 256) h[i] = 0u;
  __syncthreads();
  int base = blockIdx.x * 4096;
  int end = base + 4096 < E ? base + 4096 : E;
  for (int i = base + threadIdx.x; i < end; i += 256)
    atomicAdd(&h[batch[(size_t)t * E + i]], 1u);
  __syncthreads();
  for (int i = threadIdx.x; i < B; i += 256) {
    unsigned v = h[i];
    if (v) atomicAdd(&cnt[t * B + i], v);
  }
}

// ---- kernel 2: prefix sums --------------------------------------------

__global__ void k_scan(const unsigned* __restrict__ cnt,
                       unsigned* __restrict__ cursor) {
  __shared__ unsigned s[B];
  int tid = threadIdx.x;
  for (int t = 0; t < T; ++t) {
    unsigned v = cnt[t * B + tid];
    s[tid] = v;
    __syncthreads();
    for (int d = 1; d < B; d <<= 1) {
      unsigned x = (tid >= d) ? s[tid - d] : 0u;
      __syncthreads();
      s[tid] += x;
      __syncthreads();
    }
    cursor[t * B + tid] = s[tid] - v;  // exclusive
    __syncthreads();
  }
}

// ---- kernel 3: counting-sort scatter, LDS-local ranking ---------------
// Per-block LDS histogram -> one global atomic per distinct graph (not per
// edge): ~4x fewer, uncontended global cursor RMWs.

__global__ __launch_bounds__(256) void k_scatter(
    const int* __restrict__ batch, unsigned* __restrict__ cursor,
    unsigned* __restrict__ eid) {
  __shared__ unsigned hloc[B];
  __shared__ unsigned baseg[B];
  int t = blockIdx.y;
  int e = blockIdx.x * 256 + threadIdx.x;
  for (int i = threadIdx.x; i < B; i += 256) hloc[i] = 0u;
  __syncthreads();
  int b = 0;
  unsigned rank = 0;
  if (e < E) {
    b = batch[(size_t)t * E + e];
    rank = atomicAdd(&hloc[b], 1u);
  }
  __syncthreads();
  for (int i = threadIdx.x; i < B; i += 256) {
    unsigned cv = hloc[i];
    if (cv) baseg[i] = atomicAdd(&cursor[t * B + i], cv);
  }
  __syncthreads();
  if (e < E)
    eid[(size_t)t * E + baseg[b] + rank] = (unsigned)e | ((unsigned)b << 19);
}

// ---- kernel 4: pipelined MFMA fused score + exp + scatter -------------
// Each block owns a chunk of consecutive tiles; 2-deep pipeline: while tile
// i runs MFMA+softmax+scatter, tile i+1's 8 dwordx4 gathers are in flight
// and tile i+2's ids are being fetched (counted-vmcnt commit after scatter).
// B-fragments preloaded in 128 persistent VGPRs so no per-tile vmem touches
// the MFMA path (a per-tile B load would vmcnt(0)-drain the pipeline).

__global__ __launch_bounds__(256, 2) void k_fused(
    const float* __restrict__ ea, const unsigned* __restrict__ eid,
    const unsigned short* __restrict__ Wpack, const float* __restrict__ b1,
    const float* __restrict__ W2, const float* __restrict__ b2,
    float* __restrict__ accg, float* __restrict__ ssum) {
  __shared__ unsigned short hi_t[BLK_E * F];  // 16 KB, row-XOR-swizzled
  __shared__ unsigned short lo_t[BLK_E * F];  // 16 KB
  __shared__ float scl[BLK_E];
  __shared__ float exl[BLK_E];
  __shared__ int eidl[3][BLK_E];
  __shared__ int bblb[3][BLK_E];

  int t = blockIdx.y;
  int tid = threadIdx.x;
  const int NT = (E + BLK_E - 1) / BLK_E;
  const int CH = (NT + PB - 1) / PB;
  int t0 = blockIdx.x * CH;
  int n = NT - t0;
  if (n <= 0) return;
  if (n > CH) n = CH;

  const float* eag = ea + (size_t)t * E * (size_t)F;
  const unsigned* eidt = eid + (size_t)t * E;
  int l = tid & 63;
  int w = tid >> 6;
  int c = tid & 31;
  int r0 = tid >> 5;
  int jb = l & 15;

  // ---- persistent B-fragments (128 VGPRs) + epilogue constants ----
  const unsigned short* wpt = Wpack + (size_t)t * 16384;
  short8 bhi[4][4], blo[4][4];
#pragma unroll
  for (int nt = 0; nt < 4; ++nt)
#pragma unroll
    for (int ks = 0; ks < 4; ++ks) {
      bhi[nt][ks] = *(const short8*)(wpt + ((nt * 4 + ks) * 64 + l) * 8);
      blo[nt][ks] = *(const short8*)(wpt + 8192 + ((nt * 4 + ks) * 64 + l) * 8);
    }
  float b1r[4], w2r[4];
#pragma unroll
  for (int nt = 0; nt < 4; ++nt) {
    b1r[nt] = b1[t * H + nt * 16 + jb];
    w2r[nt] = W2[t * H + nt * 16 + jb];
  }
  float b2t = b2[t];

  // ---- prologue: ids(0), ids(1); issue gathers(0) ----
  if (tid < BLK_E) {
    int p0 = t0 * BLK_E + tid;
    if (p0 >= E) p0 = E - 1;
    unsigned pk = eidt[p0];
    eidl[0][tid] = (int)(pk & EMASK);
    bblb[0][tid] = (int)(pk >> 19);
    int p1 = (t0 + 1) * BLK_E + tid;
    if (p1 >= E) p1 = E - 1;
    pk = eidt[p1];
    eidl[1][tid] = (int)(pk & EMASK);
    bblb[1][tid] = (int)(pk >> 19);
  }
  __syncthreads();

  float4 v[8];
#pragma unroll
  for (int k = 0; k < 8; ++k) {
    int id = eidl[0][k * 8 + r0];
    v[k] = *(const float4*)(eag + (size_t)id * F + 4 * c);
  }

  for (int i = 0; i < n; ++i) {
    int ib = i % 3;
    int e0 = (t0 + i) * BLK_E;

    // A: convert tile i (vmcnt waits the gathers issued last iteration)
#pragma unroll
    for (int k = 0; k < 8; ++k) {
      int r = k * 8 + r0;
      unsigned short h0 = bfr(v[k].x), h1 = bfr(v[k].y);
      unsigned short h2 = bfr(v[k].z), h3 = bfr(v[k].w);
      ushort4 hv = {h0, h1, h2, h3};
      ushort4 lv = {bfr(v[k].x - bft(h0)), bfr(v[k].y - bft(h1)),
                    bfr(v[k].z - bft(h2)), bfr(v[k].w - bft(h3))};
      int off = (r * 256 + c * 8) ^ ((r & 7) << 4);
      *(ushort4*)((char*)hi_t + off) = hv;
      *(ushort4*)((char*)lo_t + off) = lv;
    }
    __syncthreads();  // B: tile i staged

    // C: early-issue ids(i+2) [wave 0], then gathers(i+1) [all waves]
    unsigned pk_next = 0;
    if (tid < BLK_E) {
      int p = (t0 + i + 2) * BLK_E + tid;
      if (p >= E) p = E - 1;
      pk_next = eidt[p];
    }
    if (i + 1 < n) {
      int nb = (i + 1) % 3;
#pragma unroll
      for (int k = 0; k < 8; ++k) {
        int id = eidl[nb][k * 8 + r0];
        v[k] = *(const float4*)(eag + (size_t)id * F + 4 * c);
      }
    }

    // D: MFMA on tile i (register-only operands + LDS A-frags)
    f32x4 acc[4];
#pragma unroll
    for (int nt = 0; nt < 4; ++nt) acc[nt] = (f32x4){0.f, 0.f, 0.f, 0.f};
    int arow = w * 16 + (l & 15);
    int abase = arow * 256;
    int aswz = (arow & 7) << 4;
#pragma unroll
    for (int ks = 0; ks < 4; ++ks) {
      int abyte = (abase + (ks * 32 + (l >> 4) * 8) * 2) ^ aswz;
      short8 ahi = *(const short8*)((const char*)hi_t + abyte);
      short8 alo = *(const short8*)((const char*)lo_t + abyte);
#pragma unroll
      for (int nt = 0; nt < 4; ++nt) {
        acc[nt] = __builtin_amdgcn_mfma_f32_16x16x32_bf16(ahi, bhi[nt][ks], acc[nt], 0, 0, 0);
        acc[nt] = __builtin_amdgcn_mfma_f32_16x16x32_bf16(ahi, blo[nt][ks], acc[nt], 0, 0, 0);
        acc[nt] = __builtin_amdgcn_mfma_f32_16x16x32_bf16(alo, bhi[nt][ks], acc[nt], 0, 0, 0);
      }
    }

    // epilogue: tanh + W2 dot; reduce over j within 16-lane groups
    float p0 = 0.f, p1 = 0.f, p2 = 0.f, p3 = 0.f;
#pragma unroll
    for (int nt = 0; nt < 4; ++nt) {
      p0 = fmaf(tanh_fast(acc[nt][0] + b1r[nt]), w2r[nt], p0);
      p1 = fmaf(tanh_fast(acc[nt][1] + b1r[nt]), w2r[nt], p1);
      p2 = fmaf(tanh_fast(acc[nt][2] + b1r[nt]), w2r[nt], p2);
      p3 = fmaf(tanh_fast(acc[nt][3] + b1r[nt]), w2r[nt], p3);
    }
#pragma unroll
    for (int m = 1; m < 16; m <<= 1) {
      p0 += __shfl_xor(p0, m);
      p1 += __shfl_xor(p1, m);
      p2 += __shfl_xor(p2, m);
      p3 += __shfl_xor(p3, m);
    }
    if (jb == 0) {
      int rb = w * 16 + (l >> 4) * 4;  // C/D row = (lane>>4)*4 + reg (m89)
      scl[rb + 0] = p0;
      scl[rb + 1] = p1;
      scl[rb + 2] = p2;
      scl[rb + 3] = p3;
    }
    __syncthreads();
    if (tid < BLK_E) exl[tid] = __expf(scl[tid] + b2t);
    __syncthreads();

    // F: segment-aggregated scatter + ssum (sorted edges)
    {
      int wv = tid >> 6;
      int ll = tid & 63;
      float* acct = accg + (size_t)t * B * F;
      float a0 = 0.f, a1 = 0.f, asum = 0.f;
      int prev = -1;
      for (int ii = 0; ii < 16; ++ii) {
        int eloc = wv * 16 + ii;
        if (e0 + eloc >= E) break;  // wave-uniform (tail tiles only)
        int b = bblb[ib][eloc];     // wave-uniform
        if (b != prev) {
          if (prev >= 0) {
            atomicAdd(acct + (size_t)prev * F + 2 * ll, a0);
            atomicAdd(acct + (size_t)prev * F + 2 * ll + 1, a1);
            if (ll == 0) atomicAdd(&ssum[t * B + prev], asum);
          }
          prev = b;
          a0 = 0.f;
          a1 = 0.f;
          asum = 0.f;
        }
        int off = (eloc * 256 + ll * 4) ^ ((eloc & 7) << 4);
        unsigned hv = *(const unsigned*)((const char*)hi_t + off);
        unsigned lv = *(const unsigned*)((const char*)lo_t + off);
        float x0 = bft((unsigned short)(hv & 0xFFFFu)) + bft((unsigned short)(lv & 0xFFFFu));
        float x1 = bft((unsigned short)(hv >> 16)) + bft((unsigned short)(lv >> 16));
        float exv = exl[eloc];
        a0 = fmaf(x0, exv, a0);
        a1 = fmaf(x1, exv, a1);
        asum += exv;
      }
      if (prev >= 0) {
        atomicAdd(acct + (size_t)prev * F + 2 * ll, a0);
        atomicAdd(acct + (size_t)prev * F + 2 * ll + 1, a1);
        if (ll == 0) atomicAdd(&ssum[t * B + prev], asum);
      }
    }

    // G: commit ids(i+2) (vmcnt counts past the 8 newer gather loads)
    if (tid < BLK_E) {
      eidl[(i + 2) % 3][tid] = (int)(pk_next & EMASK);
      bblb[(i + 2) % 3][tid] = (int)(pk_next >> 19);
    }
    __syncthreads();  // H: protects hi/lo/exl/scl overwrite + id buffers
  }
}

// ---- kernel 5: normalize + mean over types ----------------------------

__global__ __launch_bounds__(256) void k_final(
    const float* __restrict__ acc, const float* __restrict__ ssum,
    float* __restrict__ out) {
  int idx = blockIdx.x * 256 + threadIdx.x;  // b*F + f
  if (idx >= B * F) return;
  int b = idx >> 7;
  float s = 0.0f;
#pragma unroll
  for (int t = 0; t < T; ++t)
    s += acc[(size_t)t * B * F + idx] / ssum[t * B + b];
  out[idx] = s * (1.0f / 3.0f);
}

// ---- launch ------------------------------------------------------------

extern "C" void kernel_launch(void* const* d_in, const int* in_sizes, int n_in,
                              void* d_out, int out_size, void* d_ws, size_t ws_size,
                              hipStream_t stream) {
  const float* ea    = (const float*)d_in[0];
  const int*   batch = (const int*)d_in[1];
  const float* W1    = (const float*)d_in[2];
  const float* b1    = (const float*)d_in[3];
  const float* W2    = (const float*)d_in[4];
  const float* b2    = (const float*)d_in[5];
  float* out = (float*)d_out;

  // workspace: acc 1.5MB + ssum/cnt/cursor 36KB + eid 6MB + Wpack 96KB
  float*          acc    = (float*)d_ws;                  // T*B*F f32
  float*          ssum   = acc + (size_t)T * B * F;       // T*B f32
  unsigned*       cnt    = (unsigned*)(ssum + T * B);     // T*B u32
  unsigned*       cursor = cnt + T * B;                   // T*B u32
  unsigned*       eid    = cursor + T * B;                // T*E u32
  unsigned short* Wpack  = (unsigned short*)(eid + (size_t)T * E);  // 49152 u16

  k_init<<<(T * B * F + 255) / 256, 256, 0, stream>>>(W1, acc, ssum, cnt, Wpack);

  dim3 gh((E + 4095) / 4096, T);
  k_hist<<<gh, 256, 0, stream>>>(batch, cnt);
  k_scan<<<1, B, 0, stream>>>(cnt, cursor);
  dim3 ge((E + 255) / 256, T);
  k_scatter<<<ge, 256, 0, stream>>>(batch, cursor, eid);

  dim3 gs(PB, T);
  k_fused<<<gs, 256, 0, stream>>>(ea, eid, Wpack, b1, W2, b2, acc, ssum);

  k_final<<<(B * F + 255) / 256, 256, 0, stream>>>(acc, ssum, out);
}

// Round 12
// 390.496 us; speedup vs baseline: 6.0423x; 1.1019x over previous
//
#include <hip/hip_runtime.h>

#define T 3
#define E 500000
#define F 128
#define H 64
#define B 1024

#define BLK_E 64
#define EMASK 0x7FFFF  // e < 2^19; graph packed in bits 19..28
#define PB 1024        // blocks per type in k_fused

typedef __attribute__((ext_vector_type(8))) short short8;
typedef __attribute__((ext_vector_type(4))) float f32x4;

// ---- helpers ----------------------------------------------------------

__device__ __forceinline__ float tanh_fast(float x) {
  float e = __expf(2.0f * x);
  return 1.0f - 2.0f / (e + 1.0f);
}
__device__ __forceinline__ unsigned short bfr(float x) {  // f32->bf16 RNE
  unsigned u = __float_as_uint(x);
  return (unsigned short)((u + 0x7FFFu + ((u >> 16) & 1u)) >> 16);
}
__device__ __forceinline__ float bft(unsigned short h) {
  return __uint_as_float(((unsigned)h) << 16);
}
// pack bf16-TRUNC of (a,b) into one u32 (low16=a, high16=b): 1 v_perm_b32
__device__ __forceinline__ unsigned pk2(float a, float b) {
  return __builtin_amdgcn_perm(__float_as_uint(b), __float_as_uint(a),
                               0x07060302u);
}

// ---- kernel 0: zero accumulators + pack W1 into MFMA B-fragments ------
// Wpack[t][p(hi/lo)][nt(4)][ks(4)][lane(64)][8]: lane l holds B-frag
// col j = nt*16+(l&15), k = ks*32+(l>>4)*8 + 0..7

__global__ void k_init(const float* __restrict__ W1, float* __restrict__ acc,
                       float* __restrict__ ssum, unsigned* __restrict__ cnt,
                       unsigned short* __restrict__ Wpack) {
  int idx = blockIdx.x * blockDim.x + threadIdx.x;
  if (idx < T * B * F) acc[idx] = 0.0f;
  if (idx < T * B) {
    ssum[idx] = 0.0f;
    cnt[idx] = 0u;
  }
  if (idx < T * 2 * 4 * 4 * 64) {
    int lane = idx & 63;
    int r2 = idx >> 6;
    int ks = r2 & 3;
    int nt = (r2 >> 2) & 3;
    int p = (r2 >> 4) & 1;
    int t = r2 >> 5;
    int j = nt * 16 + (lane & 15);
#pragma unroll
    for (int e = 0; e < 8; ++e) {
      int f = ks * 32 + (lane >> 4) * 8 + e;
      float w = W1[((size_t)t * F + f) * H + j];
      unsigned short hi = bfr(w);
      unsigned short v = p ? bfr(w - bft(hi)) : hi;
      Wpack[(size_t)idx * 8 + e] = v;
    }
  }
}

// ---- kernel 1: LDS-local histogram ------------------------------------

__global__ __launch_bounds__(256) void k_hist(
    const int* __restrict__ batch, unsigned* __restrict__ cnt) {
  __shared__ unsigned h[B];
  int t = blockIdx.y;
  for (int i = threadIdx.x; i < B; i += 256) h[i] = 0u;
  __syncthreads();
  int base = blockIdx.x * 4096;
  int end = base + 4096 < E ? base + 4096 : E;
  for (int i = base + threadIdx.x; i < end; i += 256)
    atomicAdd(&h[batch[(size_t)t * E + i]], 1u);
  __syncthreads();
  for (int i = threadIdx.x; i < B; i += 256) {
    unsigned v = h[i];
    if (v) atomicAdd(&cnt[t * B + i], v);
  }
}

// ---- kernel 2: prefix sums --------------------------------------------

__global__ void k_scan(const unsigned* __restrict__ cnt,
                       unsigned* __restrict__ cursor) {
  __shared__ unsigned s[B];
  int tid = threadIdx.x;
  for (int t = 0; t < T; ++t) {
    unsigned v = cnt[t * B + tid];
    s[tid] = v;
    __syncthreads();
    for (int d = 1; d < B; d <<= 1) {
      unsigned x = (tid >= d) ? s[tid - d] : 0u;
      __syncthreads();
      s[tid] += x;
      __syncthreads();
    }
    cursor[t * B + tid] = s[tid] - v;  // exclusive
    __syncthreads();
  }
}

// ---- kernel 3: counting-sort scatter, LDS-local ranking ---------------

__global__ __launch_bounds__(256) void k_scatter(
    const int* __restrict__ batch, unsigned* __restrict__ cursor,
    unsigned* __restrict__ eid) {
  __shared__ unsigned hloc[B];
  __shared__ unsigned baseg[B];
  int t = blockIdx.y;
  int e = blockIdx.x * 256 + threadIdx.x;
  for (int i = threadIdx.x; i < B; i += 256) hloc[i] = 0u;
  __syncthreads();
  int b = 0;
  unsigned rank = 0;
  if (e < E) {
    b = batch[(size_t)t * E + e];
    rank = atomicAdd(&hloc[b], 1u);
  }
  __syncthreads();
  for (int i = threadIdx.x; i < B; i += 256) {
    unsigned cv = hloc[i];
    if (cv) baseg[i] = atomicAdd(&cursor[t * B + i], cv);
  }
  __syncthreads();
  if (e < E)
    eid[(size_t)t * E + baseg[b] + rank] = (unsigned)e | ((unsigned)b << 19);
}

// ---- kernel 4: pipelined MFMA fused score + exp + scatter -------------
// 2-deep tile pipeline (gathers for i+1 in flight during MFMA/scatter of i).
// Convert phase uses v_perm trunc-packing (hi=top16, lo=x-hi; lo*Wlo term
// ~2^-17 neglected). Scatter: exp inline from scl broadcast (one less
// barrier) + CROSS-TILE segment aggregation (flush only on graph change or
// chunk end — sorted subsequence per wave is globally non-decreasing).

__global__ __launch_bounds__(256, 2) void k_fused(
    const float* __restrict__ ea, const unsigned* __restrict__ eid,
    const unsigned short* __restrict__ Wpack, const float* __restrict__ b1,
    const float* __restrict__ W2, const float* __restrict__ b2,
    float* __restrict__ accg, float* __restrict__ ssum) {
  __shared__ unsigned short hi_t[BLK_E * F];  // 16 KB, row-XOR-swizzled
  __shared__ unsigned short lo_t[BLK_E * F];  // 16 KB
  __shared__ float scl[BLK_E];
  __shared__ int eidl[3][BLK_E];
  __shared__ int bblb[3][BLK_E];

  int t = blockIdx.y;
  int tid = threadIdx.x;
  const int NT = (E + BLK_E - 1) / BLK_E;
  const int CH = (NT + PB - 1) / PB;
  int t0 = blockIdx.x * CH;
  int n = NT - t0;
  if (n <= 0) return;
  if (n > CH) n = CH;

  const float* eag = ea + (size_t)t * E * (size_t)F;
  const unsigned* eidt = eid + (size_t)t * E;
  int l = tid & 63;
  int w = tid >> 6;
  int c = tid & 31;
  int r0 = tid >> 5;
  int jb = l & 15;

  // ---- persistent B-fragments (128 VGPRs) + epilogue constants ----
  const unsigned short* wpt = Wpack + (size_t)t * 16384;
  short8 bhi[4][4], blo[4][4];
#pragma unroll
  for (int nt = 0; nt < 4; ++nt)
#pragma unroll
    for (int ks = 0; ks < 4; ++ks) {
      bhi[nt][ks] = *(const short8*)(wpt + ((nt * 4 + ks) * 64 + l) * 8);
      blo[nt][ks] = *(const short8*)(wpt + 8192 + ((nt * 4 + ks) * 64 + l) * 8);
    }
  float b1r[4], w2r[4];
#pragma unroll
  for (int nt = 0; nt < 4; ++nt) {
    b1r[nt] = b1[t * H + nt * 16 + jb];
    w2r[nt] = W2[t * H + nt * 16 + jb];
  }
  float b2t = b2[t];

  // ---- prologue: ids(0), ids(1); issue gathers(0) ----
  if (tid < BLK_E) {
    int p0 = t0 * BLK_E + tid;
    if (p0 >= E) p0 = E - 1;
    unsigned pk = eidt[p0];
    eidl[0][tid] = (int)(pk & EMASK);
    bblb[0][tid] = (int)(pk >> 19);
    int p1 = (t0 + 1) * BLK_E + tid;
    if (p1 >= E) p1 = E - 1;
    pk = eidt[p1];
    eidl[1][tid] = (int)(pk & EMASK);
    bblb[1][tid] = (int)(pk >> 19);
  }
  __syncthreads();

  float4 v[8];
#pragma unroll
  for (int k = 0; k < 8; ++k) {
    int id = eidl[0][k * 8 + r0];
    v[k] = *(const float4*)(eag + (size_t)id * F + 4 * c);
  }

  // ---- cross-tile segment accumulators (persist across tiles) ----
  int wv = tid >> 6;
  int ll = tid & 63;
  float* acct = accg + (size_t)t * B * F;
  float a0 = 0.f, a1 = 0.f, asum = 0.f;
  int prev = -1;

  for (int i = 0; i < n; ++i) {
    int ib = i % 3;
    int e0 = (t0 + i) * BLK_E;

    // A: convert tile i (vmcnt waits the gathers issued last iteration)
#pragma unroll
    for (int k = 0; k < 8; ++k) {
      int r = k * 8 + r0;
      float4 x = v[k];
      unsigned h01 = pk2(x.x, x.y), h23 = pk2(x.z, x.w);
      float l0 = x.x - __uint_as_float(__float_as_uint(x.x) & 0xFFFF0000u);
      float l1 = x.y - __uint_as_float(__float_as_uint(x.y) & 0xFFFF0000u);
      float l2 = x.z - __uint_as_float(__float_as_uint(x.z) & 0xFFFF0000u);
      float l3 = x.w - __uint_as_float(__float_as_uint(x.w) & 0xFFFF0000u);
      unsigned lo01 = pk2(l0, l1), lo23 = pk2(l2, l3);
      int off = (r * 256 + c * 8) ^ ((r & 7) << 4);
      *(uint2*)((char*)hi_t + off) = (uint2){h01, h23};
      *(uint2*)((char*)lo_t + off) = (uint2){lo01, lo23};
    }
    __syncthreads();  // B: tile i staged

    // C: early-issue ids(i+2) [wave 0], then gathers(i+1) [all waves]
    unsigned pk_next = 0;
    if (tid < BLK_E) {
      int p = (t0 + i + 2) * BLK_E + tid;
      if (p >= E) p = E - 1;
      pk_next = eidt[p];
    }
    if (i + 1 < n) {
      int nb = (i + 1) % 3;
#pragma unroll
      for (int k = 0; k < 8; ++k) {
        int id = eidl[nb][k * 8 + r0];
        v[k] = *(const float4*)(eag + (size_t)id * F + 4 * c);
      }
    }

    // D: MFMA on tile i (register B-frags + LDS A-frags)
    f32x4 acc[4];
#pragma unroll
    for (int nt = 0; nt < 4; ++nt) acc[nt] = (f32x4){0.f, 0.f, 0.f, 0.f};
    int arow = w * 16 + (l & 15);
    int abase = arow * 256;
    int aswz = (arow & 7) << 4;
#pragma unroll
    for (int ks = 0; ks < 4; ++ks) {
      int abyte = (abase + (ks * 32 + (l >> 4) * 8) * 2) ^ aswz;
      short8 ahi = *(const short8*)((const char*)hi_t + abyte);
      short8 alo = *(const short8*)((const char*)lo_t + abyte);
#pragma unroll
      for (int nt = 0; nt < 4; ++nt) {
        acc[nt] = __builtin_amdgcn_mfma_f32_16x16x32_bf16(ahi, bhi[nt][ks], acc[nt], 0, 0, 0);
        acc[nt] = __builtin_amdgcn_mfma_f32_16x16x32_bf16(ahi, blo[nt][ks], acc[nt], 0, 0, 0);
        acc[nt] = __builtin_amdgcn_mfma_f32_16x16x32_bf16(alo, bhi[nt][ks], acc[nt], 0, 0, 0);
      }
    }

    // epilogue: tanh + W2 dot; reduce over j within 16-lane groups
    float p0 = 0.f, p1 = 0.f, p2 = 0.f, p3 = 0.f;
#pragma unroll
    for (int nt = 0; nt < 4; ++nt) {
      p0 = fmaf(tanh_fast(acc[nt][0] + b1r[nt]), w2r[nt], p0);
      p1 = fmaf(tanh_fast(acc[nt][1] + b1r[nt]), w2r[nt], p1);
      p2 = fmaf(tanh_fast(acc[nt][2] + b1r[nt]), w2r[nt], p2);
      p3 = fmaf(tanh_fast(acc[nt][3] + b1r[nt]), w2r[nt], p3);
    }
#pragma unroll
    for (int m = 1; m < 16; m <<= 1) {
      p0 += __shfl_xor(p0, m);
      p1 += __shfl_xor(p1, m);
      p2 += __shfl_xor(p2, m);
      p3 += __shfl_xor(p3, m);
    }
    if (jb == 0) {
      int rb = w * 16 + (l >> 4) * 4;  // C/D row = (lane>>4)*4 + reg (m89)
      *(float4*)&scl[rb] = (float4){p0, p1, p2, p3};
    }
    __syncthreads();  // scl(i) ready; hi/lo still valid

    // F: scatter; exp inline from scl broadcast; cross-tile aggregation
    for (int ii = 0; ii < 16; ++ii) {
      int eloc = wv * 16 + ii;
      if (e0 + eloc >= E) break;  // wave-uniform (tail tiles only)
      int b = bblb[ib][eloc];     // wave-uniform
      if (b != prev) {
        if (prev >= 0) {
          atomicAdd(acct + (size_t)prev * F + 2 * ll, a0);
          atomicAdd(acct + (size_t)prev * F + 2 * ll + 1, a1);
          if (ll == 0) atomicAdd(&ssum[t * B + prev], asum);
        }
        prev = b;
        a0 = 0.f;
        a1 = 0.f;
        asum = 0.f;
      }
      float exv = __expf(scl[eloc] + b2t);  // LDS broadcast + trans pipe
      int off = (eloc * 256 + ll * 4) ^ ((eloc & 7) << 4);
      unsigned hv = *(const unsigned*)((const char*)hi_t + off);
      unsigned lv = *(const unsigned*)((const char*)lo_t + off);
      float x0 = __uint_as_float(hv << 16) + __uint_as_float(lv << 16);
      float x1 = __uint_as_float(hv & 0xFFFF0000u) +
                 __uint_as_float(lv & 0xFFFF0000u);
      a0 = fmaf(x0, exv, a0);
      a1 = fmaf(x1, exv, a1);
      asum += exv;
    }

    // G: commit ids(i+2)
    if (tid < BLK_E) {
      eidl[(i + 2) % 3][tid] = (int)(pk_next & EMASK);
      bblb[(i + 2) % 3][tid] = (int)(pk_next >> 19);
    }
    __syncthreads();  // H: protects hi/lo/scl overwrite + id buffers
  }

  // final flush of the cross-tile segment accumulator
  if (prev >= 0) {
    atomicAdd(acct + (size_t)prev * F + 2 * ll, a0);
    atomicAdd(acct + (size_t)prev * F + 2 * ll + 1, a1);
    if (ll == 0) atomicAdd(&ssum[t * B + prev], asum);
  }
}

// ---- kernel 5: normalize + mean over types ----------------------------

__global__ __launch_bounds__(256) void k_final(
    const float* __restrict__ acc, const float* __restrict__ ssum,
    float* __restrict__ out) {
  int idx = blockIdx.x * 256 + threadIdx.x;  // b*F + f
  if (idx >= B * F) return;
  int b = idx >> 7;
  float s = 0.0f;
#pragma unroll
  for (int t = 0; t < T; ++t)
    s += acc[(size_t)t * B * F + idx] / ssum[t * B + b];
  out[idx] = s * (1.0f / 3.0f);
}

// ---- launch ------------------------------------------------------------

extern "C" void kernel_launch(void* const* d_in, const int* in_sizes, int n_in,
                              void* d_out, int out_size, void* d_ws, size_t ws_size,
                              hipStream_t stream) {
  const float* ea    = (const float*)d_in[0];
  const int*   batch = (const int*)d_in[1];
  const float* W1    = (const float*)d_in[2];
  const float* b1    = (const float*)d_in[3];
  const float* W2    = (const float*)d_in[4];
  const float* b2    = (const float*)d_in[5];
  float* out = (float*)d_out;

  // workspace: acc 1.5MB + ssum/cnt/cursor 36KB + eid 6MB + Wpack 96KB
  float*          acc    = (float*)d_ws;                  // T*B*F f32
  float*          ssum   = acc + (size_t)T * B * F;       // T*B f32
  unsigned*       cnt    = (unsigned*)(ssum + T * B);     // T*B u32
  unsigned*       cursor = cnt + T * B;                   // T*B u32
  unsigned*       eid    = cursor + T * B;                // T*E u32
  unsigned short* Wpack  = (unsigned short*)(eid + (size_t)T * E);  // 49152 u16

  k_init<<<(T * B * F + 255) / 256, 256, 0, stream>>>(W1, acc, ssum, cnt, Wpack);

  dim3 gh((E + 4095) / 4096, T);
  k_hist<<<gh, 256, 0, stream>>>(batch, cnt);
  k_scan<<<1, B, 0, stream>>>(cnt, cursor);
  dim3 ge((E + 255) / 256, T);
  k_scatter<<<ge, 256, 0, stream>>>(batch, cursor, eid);

  dim3 gs(PB, T);
  k_fused<<<gs, 256, 0, stream>>>(ea, eid, Wpack, b1, W2, b2, acc, ssum);

  k_final<<<(B * F + 255) / 256, 256, 0, stream>>>(acc, ssum, out);
}

// Round 13
// 385.938 us; speedup vs baseline: 6.1137x; 1.0118x over previous
//
#include <hip/hip_runtime.h>

#define T 3
#define E 500000
#define F 128
#define H 64
#define B 1024

#define BLK_E 64
#define EMASK 0x7FFFF  // e < 2^19; graph packed in bits 19..28
#define PB 1024        // blocks per type in k_fused

typedef __attribute__((ext_vector_type(8))) short short8;
typedef __attribute__((ext_vector_type(4))) float f32x4;

// ---- helpers ----------------------------------------------------------

__device__ __forceinline__ float tanh_fast(float x) {
  float e = __expf(2.0f * x);
  return 1.0f - 2.0f / (e + 1.0f);
}
__device__ __forceinline__ unsigned short bfr(float x) {  // f32->bf16 RNE
  unsigned u = __float_as_uint(x);
  return (unsigned short)((u + 0x7FFFu + ((u >> 16) & 1u)) >> 16);
}
__device__ __forceinline__ float bft(unsigned short h) {
  return __uint_as_float(((unsigned)h) << 16);
}
// pack bf16-TRUNC of (a,b) into one u32 (low16=a, high16=b): 1 v_perm_b32
__device__ __forceinline__ unsigned pk2(float a, float b) {
  return __builtin_amdgcn_perm(__float_as_uint(b), __float_as_uint(a),
                               0x07060302u);
}
// LDS-only barrier: waits DS ops, leaves VMEM (gather) counters UNDRAINED.
// __syncthreads() would emit s_waitcnt vmcnt(0) and kill the tile pipeline
// (m97 barrier-drain). sched_barrier(0) fences compiler motion (rule #18).
__device__ __forceinline__ void bar_lds() {
  asm volatile("s_waitcnt lgkmcnt(0)" ::: "memory");
  __builtin_amdgcn_s_barrier();
  __builtin_amdgcn_sched_barrier(0);
}

// ---- kernel 0: zero accumulators + pack W1 into MFMA B-fragments ------
// Wpack[t][p(hi/lo)][nt(4)][ks(4)][lane(64)][8]: lane l holds B-frag
// col j = nt*16+(l&15), k = ks*32+(l>>4)*8 + 0..7

__global__ void k_init(const float* __restrict__ W1, float* __restrict__ acc,
                       float* __restrict__ ssum, unsigned* __restrict__ cnt,
                       unsigned short* __restrict__ Wpack) {
  int idx = blockIdx.x * blockDim.x + threadIdx.x;
  if (idx < T * B * F) acc[idx] = 0.0f;
  if (idx < T * B) {
    ssum[idx] = 0.0f;
    cnt[idx] = 0u;
  }
  if (idx < T * 2 * 4 * 4 * 64) {
    int lane = idx & 63;
    int r2 = idx >> 6;
    int ks = r2 & 3;
    int nt = (r2 >> 2) & 3;
    int p = (r2 >> 4) & 1;
    int t = r2 >> 5;
    int j = nt * 16 + (lane & 15);
#pragma unroll
    for (int e = 0; e < 8; ++e) {
      int f = ks * 32 + (lane >> 4) * 8 + e;
      float w = W1[((size_t)t * F + f) * H + j];
      unsigned short hi = bfr(w);
      unsigned short v = p ? bfr(w - bft(hi)) : hi;
      Wpack[(size_t)idx * 8 + e] = v;
    }
  }
}

// ---- kernel 1: LDS-local histogram ------------------------------------

__global__ __launch_bounds__(256) void k_hist(
    const int* __restrict__ batch, unsigned* __restrict__ cnt) {
  __shared__ unsigned h[B];
  int t = blockIdx.y;
  for (int i = threadIdx.x; i < B; i += 256) h[i] = 0u;
  __syncthreads();
  int base = blockIdx.x * 4096;
  int end = base + 4096 < E ? base + 4096 : E;
  for (int i = base + threadIdx.x; i < end; i += 256)
    atomicAdd(&h[batch[(size_t)t * E + i]], 1u);
  __syncthreads();
  for (int i = threadIdx.x; i < B; i += 256) {
    unsigned v = h[i];
    if (v) atomicAdd(&cnt[t * B + i], v);
  }
}

// ---- kernel 2: prefix sums (one block per type) ------------------------

__global__ void k_scan(const unsigned* __restrict__ cnt,
                       unsigned* __restrict__ cursor) {
  __shared__ unsigned s[B];
  int tid = threadIdx.x;
  int t = blockIdx.x;
  unsigned v = cnt[t * B + tid];
  s[tid] = v;
  __syncthreads();
  for (int d = 1; d < B; d <<= 1) {
    unsigned x = (tid >= d) ? s[tid - d] : 0u;
    __syncthreads();
    s[tid] += x;
    __syncthreads();
  }
  cursor[t * B + tid] = s[tid] - v;  // exclusive
}

// ---- kernel 3: counting-sort scatter, LDS-local ranking ---------------

__global__ __launch_bounds__(256) void k_scatter(
    const int* __restrict__ batch, unsigned* __restrict__ cursor,
    unsigned* __restrict__ eid) {
  __shared__ unsigned hloc[B];
  __shared__ unsigned baseg[B];
  int t = blockIdx.y;
  int e = blockIdx.x * 256 + threadIdx.x;
  for (int i = threadIdx.x; i < B; i += 256) hloc[i] = 0u;
  __syncthreads();
  int b = 0;
  unsigned rank = 0;
  if (e < E) {
    b = batch[(size_t)t * E + e];
    rank = atomicAdd(&hloc[b], 1u);
  }
  __syncthreads();
  for (int i = threadIdx.x; i < B; i += 256) {
    unsigned cv = hloc[i];
    if (cv) baseg[i] = atomicAdd(&cursor[t * B + i], cv);
  }
  __syncthreads();
  if (e < E)
    eid[(size_t)t * E + baseg[b] + rank] = (unsigned)e | ((unsigned)b << 19);
}

// ---- kernel 4: pipelined MFMA fused score + exp + scatter -------------
// 2-deep tile pipeline. In-loop barriers are RAW s_barrier + lgkmcnt(0)
// (bar_lds): vmcnt never drained in the loop, so the 8 gather dwordx4 for
// tile i+1 stay in flight across all of tile i's MFMA+scatter — the convert
// phase's register dependency is the only vmcnt wait. Convert: v_perm trunc
// hi/lo split (lo*Wlo ~2^-17 neglected). Cross-tile segment aggregation.

__global__ __launch_bounds__(256, 2) void k_fused(
    const float* __restrict__ ea, const unsigned* __restrict__ eid,
    const unsigned short* __restrict__ Wpack, const float* __restrict__ b1,
    const float* __restrict__ W2, const float* __restrict__ b2,
    float* __restrict__ accg, float* __restrict__ ssum) {
  __shared__ unsigned short hi_t[BLK_E * F];  // 16 KB, row-XOR-swizzled
  __shared__ unsigned short lo_t[BLK_E * F];  // 16 KB
  __shared__ float scl[BLK_E];
  __shared__ int eidl[3][BLK_E];
  __shared__ int bblb[3][BLK_E];

  int t = blockIdx.y;
  int tid = threadIdx.x;
  const int NT = (E + BLK_E - 1) / BLK_E;
  const int CH = (NT + PB - 1) / PB;
  int t0 = blockIdx.x * CH;
  int n = NT - t0;
  if (n <= 0) return;
  if (n > CH) n = CH;

  const float* eag = ea + (size_t)t * E * (size_t)F;
  const unsigned* eidt = eid + (size_t)t * E;
  int l = tid & 63;
  int w = tid >> 6;
  int c = tid & 31;
  int r0 = tid >> 5;
  int jb = l & 15;

  // ---- persistent B-fragments (128 VGPRs) + epilogue constants ----
  const unsigned short* wpt = Wpack + (size_t)t * 16384;
  short8 bhi[4][4], blo[4][4];
#pragma unroll
  for (int nt = 0; nt < 4; ++nt)
#pragma unroll
    for (int ks = 0; ks < 4; ++ks) {
      bhi[nt][ks] = *(const short8*)(wpt + ((nt * 4 + ks) * 64 + l) * 8);
      blo[nt][ks] = *(const short8*)(wpt + 8192 + ((nt * 4 + ks) * 64 + l) * 8);
    }
  float b1r[4], w2r[4];
#pragma unroll
  for (int nt = 0; nt < 4; ++nt) {
    b1r[nt] = b1[t * H + nt * 16 + jb];
    w2r[nt] = W2[t * H + nt * 16 + jb];
  }
  float b2t = b2[t];

  // ---- prologue: ids(0), ids(1); issue gathers(0) ----
  if (tid < BLK_E) {
    int p0 = t0 * BLK_E + tid;
    if (p0 >= E) p0 = E - 1;
    unsigned pk = eidt[p0];
    eidl[0][tid] = (int)(pk & EMASK);
    bblb[0][tid] = (int)(pk >> 19);
    int p1 = (t0 + 1) * BLK_E + tid;
    if (p1 >= E) p1 = E - 1;
    pk = eidt[p1];
    eidl[1][tid] = (int)(pk & EMASK);
    bblb[1][tid] = (int)(pk >> 19);
  }
  __syncthreads();

  float4 v[8];
#pragma unroll
  for (int k = 0; k < 8; ++k) {
    int id = eidl[0][k * 8 + r0];
    v[k] = *(const float4*)(eag + (size_t)id * F + 4 * c);
  }

  // ---- cross-tile segment accumulators (persist across tiles) ----
  int wv = tid >> 6;
  int ll = tid & 63;
  float* acct = accg + (size_t)t * B * F;
  float a0 = 0.f, a1 = 0.f, asum = 0.f;
  int prev = -1;

  for (int i = 0; i < n; ++i) {
    int ib = i % 3;
    int e0 = (t0 + i) * BLK_E;

    // A: convert tile i (register dep on v[] = the only vmcnt wait)
#pragma unroll
    for (int k = 0; k < 8; ++k) {
      int r = k * 8 + r0;
      float4 x = v[k];
      unsigned h01 = pk2(x.x, x.y), h23 = pk2(x.z, x.w);
      float l0 = x.x - __uint_as_float(__float_as_uint(x.x) & 0xFFFF0000u);
      float l1 = x.y - __uint_as_float(__float_as_uint(x.y) & 0xFFFF0000u);
      float l2 = x.z - __uint_as_float(__float_as_uint(x.z) & 0xFFFF0000u);
      float l3 = x.w - __uint_as_float(__float_as_uint(x.w) & 0xFFFF0000u);
      unsigned lo01 = pk2(l0, l1), lo23 = pk2(l2, l3);
      int off = (r * 256 + c * 8) ^ ((r & 7) << 4);
      *(uint2*)((char*)hi_t + off) = (uint2){h01, h23};
      *(uint2*)((char*)lo_t + off) = (uint2){lo01, lo23};
    }
    bar_lds();  // B: tile i staged (vmcnt untouched)

    // C: early-issue ids(i+2) [first], then gathers(i+1) — in-order vmcnt
    // means later waits on ids leave the 8 newer gathers outstanding.
    unsigned pk_next = 0;
    if (tid < BLK_E) {
      int p = (t0 + i + 2) * BLK_E + tid;
      if (p >= E) p = E - 1;
      pk_next = eidt[p];
    }
    if (i + 1 < n) {
      int nb = (i + 1) % 3;
#pragma unroll
      for (int k = 0; k < 8; ++k) {
        int id = eidl[nb][k * 8 + r0];
        v[k] = *(const float4*)(eag + (size_t)id * F + 4 * c);
      }
    }

    // D: MFMA on tile i (register B-frags + LDS A-frags)
    f32x4 acc[4];
#pragma unroll
    for (int nt = 0; nt < 4; ++nt) acc[nt] = (f32x4){0.f, 0.f, 0.f, 0.f};
    int arow = w * 16 + (l & 15);
    int abase = arow * 256;
    int aswz = (arow & 7) << 4;
#pragma unroll
    for (int ks = 0; ks < 4; ++ks) {
      int abyte = (abase + (ks * 32 + (l >> 4) * 8) * 2) ^ aswz;
      short8 ahi = *(const short8*)((const char*)hi_t + abyte);
      short8 alo = *(const short8*)((const char*)lo_t + abyte);
#pragma unroll
      for (int nt = 0; nt < 4; ++nt) {
        acc[nt] = __builtin_amdgcn_mfma_f32_16x16x32_bf16(ahi, bhi[nt][ks], acc[nt], 0, 0, 0);
        acc[nt] = __builtin_amdgcn_mfma_f32_16x16x32_bf16(ahi, blo[nt][ks], acc[nt], 0, 0, 0);
        acc[nt] = __builtin_amdgcn_mfma_f32_16x16x32_bf16(alo, bhi[nt][ks], acc[nt], 0, 0, 0);
      }
    }

    // epilogue: tanh + W2 dot; reduce over j within 16-lane groups
    float p0 = 0.f, p1 = 0.f, p2 = 0.f, p3 = 0.f;
#pragma unroll
    for (int nt = 0; nt < 4; ++nt) {
      p0 = fmaf(tanh_fast(acc[nt][0] + b1r[nt]), w2r[nt], p0);
      p1 = fmaf(tanh_fast(acc[nt][1] + b1r[nt]), w2r[nt], p1);
      p2 = fmaf(tanh_fast(acc[nt][2] + b1r[nt]), w2r[nt], p2);
      p3 = fmaf(tanh_fast(acc[nt][3] + b1r[nt]), w2r[nt], p3);
    }
#pragma unroll
    for (int m = 1; m < 16; m <<= 1) {
      p0 += __shfl_xor(p0, m);
      p1 += __shfl_xor(p1, m);
      p2 += __shfl_xor(p2, m);
      p3 += __shfl_xor(p3, m);
    }
    if (jb == 0) {
      int rb = w * 16 + (l >> 4) * 4;  // C/D row = (lane>>4)*4 + reg (m89)
      *(float4*)&scl[rb] = (float4){p0, p1, p2, p3};
    }
    bar_lds();  // E: scl(i) ready; hi/lo still valid; vmcnt untouched

    // F: scatter; exp inline from scl broadcast; cross-tile aggregation
    for (int ii = 0; ii < 16; ++ii) {
      int eloc = wv * 16 + ii;
      if (e0 + eloc >= E) break;  // wave-uniform (tail tiles only)
      int b = bblb[ib][eloc];     // wave-uniform
      if (b != prev) {
        if (prev >= 0) {
          atomicAdd(acct + (size_t)prev * F + 2 * ll, a0);
          atomicAdd(acct + (size_t)prev * F + 2 * ll + 1, a1);
          if (ll == 0) atomicAdd(&ssum[t * B + prev], asum);
        }
        prev = b;
        a0 = 0.f;
        a1 = 0.f;
        asum = 0.f;
      }
      float exv = __expf(scl[eloc] + b2t);  // LDS broadcast + trans pipe
      int off = (eloc * 256 + ll * 4) ^ ((eloc & 7) << 4);
      unsigned hv = *(const unsigned*)((const char*)hi_t + off);
      unsigned lv = *(const unsigned*)((const char*)lo_t + off);
      float x0 = __uint_as_float(hv << 16) + __uint_as_float(lv << 16);
      float x1 = __uint_as_float(hv & 0xFFFF0000u) +
                 __uint_as_float(lv & 0xFFFF0000u);
      a0 = fmaf(x0, exv, a0);
      a1 = fmaf(x1, exv, a1);
      asum += exv;
    }

    // G: commit ids(i+2); the ds_write's dependency waits vmcnt only down
    // to the id load (oldest) — the 8 newer gathers remain in flight.
    if (tid < BLK_E) {
      eidl[(i + 2) % 3][tid] = (int)(pk_next & EMASK);
      bblb[(i + 2) % 3][tid] = (int)(pk_next >> 19);
    }
    bar_lds();  // H: protects hi/lo/scl overwrite + id buffers
  }

  // final flush of the cross-tile segment accumulator
  if (prev >= 0) {
    atomicAdd(acct + (size_t)prev * F + 2 * ll, a0);
    atomicAdd(acct + (size_t)prev * F + 2 * ll + 1, a1);
    if (ll == 0) atomicAdd(&ssum[t * B + prev], asum);
  }
}

// ---- kernel 5: normalize + mean over types ----------------------------

__global__ __launch_bounds__(256) void k_final(
    const float* __restrict__ acc, const float* __restrict__ ssum,
    float* __restrict__ out) {
  int idx = blockIdx.x * 256 + threadIdx.x;  // b*F + f
  if (idx >= B * F) return;
  int b = idx >> 7;
  float s = 0.0f;
#pragma unroll
  for (int t = 0; t < T; ++t)
    s += acc[(size_t)t * B * F + idx] / ssum[t * B + b];
  out[idx] = s * (1.0f / 3.0f);
}

// ---- launch ------------------------------------------------------------

extern "C" void kernel_launch(void* const* d_in, const int* in_sizes, int n_in,
                              void* d_out, int out_size, void* d_ws, size_t ws_size,
                              hipStream_t stream) {
  const float* ea    = (const float*)d_in[0];
  const int*   batch = (const int*)d_in[1];
  const float* W1    = (const float*)d_in[2];
  const float* b1    = (const float*)d_in[3];
  const float* W2    = (const float*)d_in[4];
  const float* b2    = (const float*)d_in[5];
  float* out = (float*)d_out;

  // workspace: acc 1.5MB + ssum/cnt/cursor 36KB + eid 6MB + Wpack 96KB
  float*          acc    = (float*)d_ws;                  // T*B*F f32
  float*          ssum   = acc + (size_t)T * B * F;       // T*B f32
  unsigned*       cnt    = (unsigned*)(ssum + T * B);     // T*B u32
  unsigned*       cursor = cnt + T * B;                   // T*B u32
  unsigned*       eid    = cursor + T * B;                // T*E u32
  unsigned short* Wpack  = (unsigned short*)(eid + (size_t)T * E);  // 49152 u16

  k_init<<<(T * B * F + 255) / 256, 256, 0, stream>>>(W1, acc, ssum, cnt, Wpack);

  dim3 gh((E + 4095) / 4096, T);
  k_hist<<<gh, 256, 0, stream>>>(batch, cnt);
  k_scan<<<T, B, 0, stream>>>(cnt, cursor);
  dim3 ge((E + 255) / 256, T);
  k_scatter<<<ge, 256, 0, stream>>>(batch, cursor, eid);

  dim3 gs(PB, T);
  k_fused<<<gs, 256, 0, stream>>>(ea, eid, Wpack, b1, W2, b2, acc, ssum);

  k_final<<<(B * F + 255) / 256, 256, 0, stream>>>(acc, ssum, out);
}